// Round 14
// baseline (1567.724 us; speedup 1.0000x reference)
//
#include <hip/hip_runtime.h>
#include <hip/hip_bf16.h>
#include <stdint.h>

typedef __bf16 bf16_t;
typedef __bf16 bf16x4 __attribute__((ext_vector_type(4)));
typedef __bf16 bf16x8 __attribute__((ext_vector_type(8)));
typedef float f32x4 __attribute__((ext_vector_type(4)));

#define LDS_CAST(p) ((__attribute__((address_space(3))) void*)(p))
#define GLB_CAST(p) ((const __attribute__((address_space(1))) void*)(p))

__device__ __forceinline__ void gl_lds16(const void* g, void* l) {
  __builtin_amdgcn_global_load_lds(GLB_CAST(g), LDS_CAST(l), 16, 0, 0);
}

#define MFMA16(a,b,c) __builtin_amdgcn_mfma_f32_16x16x32_bf16((a),(b),(c),0,0,0)
#define BARRIER() __builtin_amdgcn_s_barrier()
#define PRIO(n)  __builtin_amdgcn_s_setprio(n)

template<int N> __device__ __forceinline__ void vmw() {
  if constexpr (N == 8)      asm volatile("s_waitcnt vmcnt(8)" ::: "memory");
  else if constexpr (N == 4) asm volatile("s_waitcnt vmcnt(4)" ::: "memory");
  else if constexpr (N == 0) asm volatile("s_waitcnt vmcnt(0)" ::: "memory");
  // N == -1: no wait
}

static constexpr int M_TOT = 4096, H_DIM = 4096, I_DIM = 14336;

// ---------------------------------------------------------------------------
// fp32 -> bf16 conversion of X, Wg, Wu in ONE launch (grid-stride x3)
// ---------------------------------------------------------------------------
__global__ __launch_bounds__(256)
void k_conv3(const float4* __restrict__ x,  const float4* __restrict__ wg,
             const float4* __restrict__ wu, bf16x4* __restrict__ Xb,
             bf16x4* __restrict__ Wgb, bf16x4* __restrict__ Wub,
             long nX, long nW)
{
  const long stride = (long)gridDim.x * blockDim.x;
  const long t0 = (long)blockIdx.x * blockDim.x + threadIdx.x;
  for (long i = t0; i < nX; i += stride) {
    float4 v = x[i]; bf16x4 o;
    o[0] = (bf16_t)v.x; o[1] = (bf16_t)v.y; o[2] = (bf16_t)v.z; o[3] = (bf16_t)v.w;
    Xb[i] = o;
  }
  for (long i = t0; i < nW; i += stride) {
    float4 v = wg[i]; bf16x4 o;
    o[0] = (bf16_t)v.x; o[1] = (bf16_t)v.y; o[2] = (bf16_t)v.z; o[3] = (bf16_t)v.w;
    Wgb[i] = o;
  }
  for (long i = t0; i < nW; i += stride) {
    float4 v = wu[i]; bf16x4 o;
    o[0] = (bf16_t)v.x; o[1] = (bf16_t)v.y; o[2] = (bf16_t)v.z; o[3] = (bf16_t)v.w;
    Wub[i] = o;
  }
}

// ---------------------------------------------------------------------------
// fp32 -> bf16 conversion (single tensor), for Wd after gateup
// ---------------------------------------------------------------------------
__global__ __launch_bounds__(256)
void k_conv(const float4* __restrict__ src, bf16x4* __restrict__ dst, long n4)
{
  long stride = (long)gridDim.x * blockDim.x;
  for (long i = (long)blockIdx.x * blockDim.x + threadIdx.x; i < n4; i += stride) {
    float4 v = src[i];
    bf16x4 o;
    o[0] = (bf16_t)v.x; o[1] = (bf16_t)v.y; o[2] = (bf16_t)v.z; o[3] = (bf16_t)v.w;
    dst[i] = o;
  }
}

// ===========================================================================
// GEMM1 (R9 schedule, unroll-4 constant-folded addressing):
// A[M,I] = silu(X Wg^T)*(X Wu^T). BM=256, BN=128, BK=32, dist-1 register
// fragment prefetch, 4 LDS bufs x 32 KiB, lead-3, vmw(4)+barrier per tile.
// All buffer bases are compile-time constants; global ptrs advance 128/iter.
// ===========================================================================
__global__ __launch_bounds__(512, 2)
void k_gateup9(const bf16_t* __restrict__ X, const bf16_t* __restrict__ Wg,
               const bf16_t* __restrict__ Wu, bf16_t* __restrict__ Aout)
{
  __shared__ __align__(1024) char lds[131072];
  const int tid = threadIdx.x, wave = tid >> 6, lane = tid & 63;
  const int lr = lane & 15, kg = lane >> 4;
  const int xm = ((lr >> 3) & 1) << 5;
  const int wm = wave >> 2, wn = wave & 3;
  const int wb = wave * 1024;

  const int bid = blockIdx.x;                 // grid = 1792
  const int bq  = bid >> 3;                   // 0..223
  const int tn  = (bid & 7) * 14 + (bq >> 4); // 0..111
  const int tm  = bq & 15;                    // 0..15

  const int srow  = tid >> 2;                                   // 0..127
  const int scolb = ((tid & 3) * 16) ^ (((tid >> 5) & 1) << 5); // pre-swizzled

  const bf16_t* gX = X  + (size_t)(tm * 256 + srow) * H_DIM + (scolb >> 1);
  const bf16_t* gG = Wg + (size_t)(tn * 128 + srow) * H_DIM + (scolb >> 1);
  const bf16_t* gU = Wu + (size_t)(tn * 128 + srow) * H_DIM + (scolb >> 1);
  const size_t xh = (size_t)128 * H_DIM;

  const int ck   = (kg * 16) ^ xm;
  const int offA = (wm * 128 + lr) * 64 + ck;            // + f*1024, f=0..7
  const int offG = 16384 + (wn * 32 + lr) * 64 + ck;     // + n*1024, n=0..1
  const int offU = offG + 8192;

  const f32x4 vz = {0.f, 0.f, 0.f, 0.f};
  f32x4 accg[8][2], accu[8][2];
#pragma unroll
  for (int m = 0; m < 8; ++m)
#pragma unroll
    for (int n = 0; n < 2; ++n) { accg[m][n] = vz; accu[m][n] = vz; }

  // constant buffer bases
  const char* B0r = lds;            const char* B1r = lds + 32768;
  const char* B2r = lds + 65536;    const char* B3r = lds + 98304;
  char* S0 = lds + wb;              char* S1 = lds + 32768 + wb;
  char* S2 = lds + 65536 + wb;      char* S3 = lds + 98304 + wb;

#define G1_STAGE_AT(SB, KC)                                                  \
  { gl_lds16(gX + (KC),      (SB));                                          \
    gl_lds16(gX + xh + (KC), (SB) + 8192);                                   \
    gl_lds16(gG + (KC),      (SB) + 16384);                                  \
    gl_lds16(gU + (KC),      (SB) + 24576); }

#define G1_READS_AT(SET, RB)                                                 \
  { _Pragma("unroll") for (int f = 0; f < 8; ++f)                            \
      a##SET[f] = *(const bf16x8*)((RB) + offA + f * 1024);                  \
    _Pragma("unroll") for (int n = 0; n < 2; ++n) {                          \
      bg##SET[n] = *(const bf16x8*)((RB) + offG + n * 1024);                 \
      bu##SET[n] = *(const bf16x8*)((RB) + offU + n * 1024); } }

#define G1_MFMA(SET)                                                         \
  { PRIO(1);                                                                 \
    _Pragma("unroll") for (int m = 0; m < 8; ++m)                            \
    _Pragma("unroll") for (int n = 0; n < 2; ++n) {                          \
      accg[m][n] = MFMA16(a##SET[m], bg##SET[n], accg[m][n]);                \
      accu[m][n] = MFMA16(a##SET[m], bu##SET[n], accu[m][n]); }              \
    PRIO(0); }

  bf16x8 aA[8], bgA[2], buA[2];
  bf16x8 aB[8], bgB[2], buB[2];

  // prologue: stage tiles 0..2, read frags(0) into set A
  G1_STAGE_AT(S0, 0); G1_STAGE_AT(S1, 32); G1_STAGE_AT(S2, 64);
  vmw<8>(); BARRIER();
  G1_READS_AT(A, B0r);

  // main: 31 iterations x 4 tiles = tiles 0..123 (NT = 128)
#pragma unroll 1
  for (int it = 0; it < 31; ++it) {
    vmw<4>(); BARRIER(); G1_READS_AT(B, B1r); G1_STAGE_AT(S3, 96);  G1_MFMA(A);
    vmw<4>(); BARRIER(); G1_READS_AT(A, B2r); G1_STAGE_AT(S0, 128); G1_MFMA(B);
    vmw<4>(); BARRIER(); G1_READS_AT(B, B3r); G1_STAGE_AT(S1, 160); G1_MFMA(A);
    vmw<4>(); BARRIER(); G1_READS_AT(A, B0r); G1_STAGE_AT(S2, 192); G1_MFMA(B);
    gX += 128; gG += 128; gU += 128;
  }
  // tail: tiles 124..127 (bufs 0..3); A holds frags(124); staged thru 126
  vmw<4>(); BARRIER(); G1_READS_AT(B, B1r); G1_STAGE_AT(S3, 96); G1_MFMA(A);
  vmw<4>(); BARRIER(); G1_READS_AT(A, B2r);                      G1_MFMA(B);
  vmw<0>(); BARRIER(); G1_READS_AT(B, B3r);                      G1_MFMA(A);
  G1_MFMA(B);
#undef G1_STAGE_AT
#undef G1_READS_AT
#undef G1_MFMA

  // epilogue: C/D col = lane&15, row = (lane>>4)*4 + e
  const int r0 = tm * 256 + wm * 128 + kg * 4;
  const int c0 = tn * 128 + wn * 32 + lr;
#pragma unroll
  for (int m = 0; m < 8; ++m)
#pragma unroll
    for (int n = 0; n < 2; ++n)
#pragma unroll
      for (int e = 0; e < 4; ++e) {
        float g = accg[m][n][e];
        float u = accu[m][n][e];
        float s = g / (1.0f + __expf(-g));
        Aout[(size_t)(r0 + m * 16 + e) * I_DIM + c0 + n * 16] = (bf16_t)(s * u);
      }
}

// ===========================================================================
// GEMM2 (R9 schedule, unroll-4 constant-folded addressing):
// D[M,H] = A Wd^T. BM=BN=256, BK=32, dist-1 register fragment prefetch,
// 4 bufs x 32 KiB (A 16K | B 16K), lead-3, vmw(4)+barrier per tile.
// ===========================================================================
__global__ __launch_bounds__(512, 2)
void k_down9(const bf16_t* __restrict__ Aa, const bf16_t* __restrict__ Wd,
             float* __restrict__ D)
{
  __shared__ __align__(1024) char lds[131072];
  const int tid = threadIdx.x, wave = tid >> 6, lane = tid & 63;
  const int lr = lane & 15, kg = lane >> 4;
  const int xm = ((lr >> 3) & 1) << 5;
  const int wm = wave >> 2, wn = wave & 3;
  const int wb = wave * 1024;

  const int bid = blockIdx.x;                 // grid = 256
  const int bq  = bid >> 3;                   // 0..31
  const int tn  = (bid & 7) * 2 + (bq >> 4);  // 0..15
  const int tm  = bq & 15;                    // 0..15

  const int srow  = tid >> 2;
  const int scolb = ((tid & 3) * 16) ^ (((tid >> 5) & 1) << 5);

  const bf16_t* gA = Aa + (size_t)(tm * 256 + srow) * I_DIM + (scolb >> 1);
  const bf16_t* gB = Wd + (size_t)(tn * 256 + srow) * I_DIM + (scolb >> 1);
  const size_t hI = (size_t)128 * I_DIM;

  const int ck   = (kg * 16) ^ xm;
  const int offA = (wm * 128 + lr) * 64 + ck;            // + f*1024
  const int offB = 16384 + (wn * 64 + lr) * 64 + ck;     // + n*1024, n=0..3

  const f32x4 vz = {0.f, 0.f, 0.f, 0.f};
  f32x4 acc[8][4];
#pragma unroll
  for (int m = 0; m < 8; ++m)
#pragma unroll
    for (int n = 0; n < 4; ++n) acc[m][n] = vz;

  const char* B0r = lds;            const char* B1r = lds + 32768;
  const char* B2r = lds + 65536;    const char* B3r = lds + 98304;
  char* S0 = lds + wb;              char* S1 = lds + 32768 + wb;
  char* S2 = lds + 65536 + wb;      char* S3 = lds + 98304 + wb;

#define G2_STAGE_AT(SB, KC)                                                  \
  { gl_lds16(gA + (KC),      (SB));                                          \
    gl_lds16(gA + hI + (KC), (SB) + 8192);                                   \
    gl_lds16(gB + (KC),      (SB) + 16384);                                  \
    gl_lds16(gB + hI + (KC), (SB) + 24576); }

#define G2_READS_AT(SET, RB)                                                 \
  { _Pragma("unroll") for (int f = 0; f < 8; ++f)                            \
      a##SET[f] = *(const bf16x8*)((RB) + offA + f * 1024);                  \
    _Pragma("unroll") for (int n = 0; n < 4; ++n)                            \
      b##SET[n] = *(const bf16x8*)((RB) + offB + n * 1024); }

#define G2_MFMA(SET)                                                         \
  { PRIO(1);                                                                 \
    _Pragma("unroll") for (int m = 0; m < 8; ++m)                            \
    _Pragma("unroll") for (int n = 0; n < 4; ++n)                            \
      acc[m][n] = MFMA16(a##SET[m], b##SET[n], acc[m][n]);                   \
    PRIO(0); }

  bf16x8 aA[8], bA[4];
  bf16x8 aB[8], bB[4];

  G2_STAGE_AT(S0, 0); G2_STAGE_AT(S1, 32); G2_STAGE_AT(S2, 64);
  vmw<8>(); BARRIER();
  G2_READS_AT(A, B0r);

  // main: 111 iterations x 4 tiles = tiles 0..443 (NT = 448)
#pragma unroll 1
  for (int it = 0; it < 111; ++it) {
    vmw<4>(); BARRIER(); G2_READS_AT(B, B1r); G2_STAGE_AT(S3, 96);  G2_MFMA(A);
    vmw<4>(); BARRIER(); G2_READS_AT(A, B2r); G2_STAGE_AT(S0, 128); G2_MFMA(B);
    vmw<4>(); BARRIER(); G2_READS_AT(B, B3r); G2_STAGE_AT(S1, 160); G2_MFMA(A);
    vmw<4>(); BARRIER(); G2_READS_AT(A, B0r); G2_STAGE_AT(S2, 192); G2_MFMA(B);
    gA += 128; gB += 128;
  }
  // tail: tiles 444..447
  vmw<4>(); BARRIER(); G2_READS_AT(B, B1r); G2_STAGE_AT(S3, 96); G2_MFMA(A);
  vmw<4>(); BARRIER(); G2_READS_AT(A, B2r);                      G2_MFMA(B);
  vmw<0>(); BARRIER(); G2_READS_AT(B, B3r);                      G2_MFMA(A);
  G2_MFMA(B);
#undef G2_STAGE_AT
#undef G2_READS_AT
#undef G2_MFMA

  const int r0 = tm * 256 + wm * 128 + kg * 4;
  const int c0 = tn * 256 + wn * 64 + lr;
#pragma unroll
  for (int m = 0; m < 8; ++m)
#pragma unroll
    for (int n = 0; n < 4; ++n)
#pragma unroll
      for (int e = 0; e < 4; ++e)
        D[(size_t)(r0 + m * 16 + e) * H_DIM + c0 + n * 16] = acc[m][n][e];
}

// ---------------------------------------------------------------------------
extern "C" void kernel_launch(void* const* d_in, const int* in_sizes, int n_in,
                              void* d_out, int out_size, void* d_ws, size_t ws_size,
                              hipStream_t stream) {
  const float* x  = (const float*)d_in[0];
  const float* wg = (const float*)d_in[1];
  const float* wu = (const float*)d_in[2];
  const float* wd = (const float*)d_in[3];
  float* out = (float*)d_out;

  const size_t A_BYTES = (size_t)M_TOT * I_DIM * 2;
  const size_t X_BYTES = (size_t)M_TOT * H_DIM * 2;
  const size_t W_BYTES = (size_t)I_DIM * H_DIM * 2;
  char* ws = (char*)d_ws;
  bf16_t* Ab  = (bf16_t*)(ws);
  bf16_t* Xb  = (bf16_t*)(ws + A_BYTES);
  bf16_t* Wgb = (bf16_t*)(ws + A_BYTES + X_BYTES);
  bf16_t* Wub = (bf16_t*)(ws + A_BYTES + X_BYTES + W_BYTES);
  bf16_t* Wdb = Wgb;   // reuse after k_gateup9 consumed Wgb

  const long nX = (long)M_TOT * H_DIM / 4;
  const long nW = (long)I_DIM * H_DIM / 4;

  k_conv3<<<dim3(2048), dim3(256), 0, stream>>>(
      (const float4*)x, (const float4*)wg, (const float4*)wu,
      (bf16x4*)Xb, (bf16x4*)Wgb, (bf16x4*)Wub, nX, nW);

  k_gateup9<<<dim3(16 * 112), dim3(512), 0, stream>>>(Xb, Wgb, Wub, Ab);

  k_conv<<<dim3(2048), dim3(256), 0, stream>>>((const float4*)wd, (bf16x4*)Wdb, nW);

  k_down9<<<dim3(16 * 16), dim3(512), 0, stream>>>(Ab, Wdb, out);
}

// Round 15
// 1419.546 us; speedup vs baseline: 1.1044x; 1.1044x over previous
//
#include <hip/hip_runtime.h>
#include <hip/hip_bf16.h>
#include <stdint.h>

typedef __bf16 bf16_t;
typedef __bf16 bf16x4 __attribute__((ext_vector_type(4)));
typedef __bf16 bf16x8 __attribute__((ext_vector_type(8)));
typedef float f32x4 __attribute__((ext_vector_type(4)));

#define LDS_CAST(p) ((__attribute__((address_space(3))) void*)(p))
#define GLB_CAST(p) ((const __attribute__((address_space(1))) void*)(p))

__device__ __forceinline__ void gl_lds16(const void* g, void* l) {
  __builtin_amdgcn_global_load_lds(GLB_CAST(g), LDS_CAST(l), 16, 0, 0);
}

#define MFMA16(a,b,c) __builtin_amdgcn_mfma_f32_16x16x32_bf16((a),(b),(c),0,0,0)
#define BARRIER() __builtin_amdgcn_s_barrier()
#define PRIO(n)  __builtin_amdgcn_s_setprio(n)

template<int N> __device__ __forceinline__ void vmw() {
  if constexpr (N == 8)      asm volatile("s_waitcnt vmcnt(8)" ::: "memory");
  else if constexpr (N == 4) asm volatile("s_waitcnt vmcnt(4)" ::: "memory");
  else if constexpr (N == 0) asm volatile("s_waitcnt vmcnt(0)" ::: "memory");
  // N == -1: no wait
}

static constexpr int M_TOT = 4096, H_DIM = 4096, I_DIM = 14336;

// ---------------------------------------------------------------------------
// fp32 -> bf16 conversion of X, Wg, Wu in ONE launch (grid-stride x3)
// ---------------------------------------------------------------------------
__global__ __launch_bounds__(256)
void k_conv3(const float4* __restrict__ x,  const float4* __restrict__ wg,
             const float4* __restrict__ wu, bf16x4* __restrict__ Xb,
             bf16x4* __restrict__ Wgb, bf16x4* __restrict__ Wub,
             long nX, long nW)
{
  const long stride = (long)gridDim.x * blockDim.x;
  const long t0 = (long)blockIdx.x * blockDim.x + threadIdx.x;
  for (long i = t0; i < nX; i += stride) {
    float4 v = x[i]; bf16x4 o;
    o[0] = (bf16_t)v.x; o[1] = (bf16_t)v.y; o[2] = (bf16_t)v.z; o[3] = (bf16_t)v.w;
    Xb[i] = o;
  }
  for (long i = t0; i < nW; i += stride) {
    float4 v = wg[i]; bf16x4 o;
    o[0] = (bf16_t)v.x; o[1] = (bf16_t)v.y; o[2] = (bf16_t)v.z; o[3] = (bf16_t)v.w;
    Wgb[i] = o;
  }
  for (long i = t0; i < nW; i += stride) {
    float4 v = wu[i]; bf16x4 o;
    o[0] = (bf16_t)v.x; o[1] = (bf16_t)v.y; o[2] = (bf16_t)v.z; o[3] = (bf16_t)v.w;
    Wub[i] = o;
  }
}

// ---------------------------------------------------------------------------
// fp32 -> bf16 conversion (single tensor), for Wd after gateup
// ---------------------------------------------------------------------------
__global__ __launch_bounds__(256)
void k_conv(const float4* __restrict__ src, bf16x4* __restrict__ dst, long n4)
{
  long stride = (long)gridDim.x * blockDim.x;
  for (long i = (long)blockIdx.x * blockDim.x + threadIdx.x; i < n4; i += stride) {
    float4 v = src[i];
    bf16x4 o;
    o[0] = (bf16_t)v.x; o[1] = (bf16_t)v.y; o[2] = (bf16_t)v.z; o[3] = (bf16_t)v.w;
    dst[i] = o;
  }
}

// ===========================================================================
// GEMM1 (R9 verbatim — measured best): A[M,I] = silu(X Wg^T)*(X Wu^T).
// BM=256, BN=128, BK=32, distance-1 register fragment prefetch,
// 4 LDS bufs x 32 KiB, lead-3 staging, 1 vmcnt+1 barrier per tile.
// ===========================================================================
__global__ __launch_bounds__(512, 2)
void k_gateup9(const bf16_t* __restrict__ X, const bf16_t* __restrict__ Wg,
               const bf16_t* __restrict__ Wu, bf16_t* __restrict__ Aout)
{
  __shared__ __align__(1024) char lds[131072];
  const int tid = threadIdx.x, wave = tid >> 6, lane = tid & 63;
  const int lr = lane & 15, kg = lane >> 4;
  const int xm = ((lr >> 3) & 1) << 5;
  const int wm = wave >> 2, wn = wave & 3;
  const int wb = wave * 1024;

  const int bid = blockIdx.x;                 // grid = 1792
  const int bq  = bid >> 3;                   // 0..223
  const int tn  = (bid & 7) * 14 + (bq >> 4); // 0..111
  const int tm  = bq & 15;                    // 0..15

  const int srow  = tid >> 2;                                   // 0..127
  const int scolb = ((tid & 3) * 16) ^ (((tid >> 5) & 1) << 5); // pre-swizzled

  const bf16_t* gX = X  + (size_t)(tm * 256 + srow) * H_DIM + (scolb >> 1);
  const bf16_t* gG = Wg + (size_t)(tn * 128 + srow) * H_DIM + (scolb >> 1);
  const bf16_t* gU = Wu + (size_t)(tn * 128 + srow) * H_DIM + (scolb >> 1);
  const size_t xh = (size_t)128 * H_DIM;

  const int ck   = (kg * 16) ^ xm;
  const int offA = (wm * 128 + lr) * 64 + ck;            // + f*1024, f=0..7
  const int offG = 16384 + (wn * 32 + lr) * 64 + ck;     // + n*1024, n=0..1
  const int offU = offG + 8192;

  const f32x4 vz = {0.f, 0.f, 0.f, 0.f};
  f32x4 accg[8][2], accu[8][2];
#pragma unroll
  for (int m = 0; m < 8; ++m)
#pragma unroll
    for (int n = 0; n < 2; ++n) { accg[m][n] = vz; accu[m][n] = vz; }

#define G1_STAGE(TT)                                                         \
  { char* sb = lds + (((TT) & 3) << 15) + wb;                                \
    const int kc = (TT) * 32;                                                \
    gl_lds16(gX + kc,      sb);                                              \
    gl_lds16(gX + xh + kc, sb + 8192);                                       \
    gl_lds16(gG + kc,      sb + 16384);                                      \
    gl_lds16(gU + kc,      sb + 24576); }

#define G1_READS(SET, TT)                                                    \
  { const char* rb = lds + (((TT) & 3) << 15);                               \
    _Pragma("unroll") for (int f = 0; f < 8; ++f)                            \
      a##SET[f] = *(const bf16x8*)(rb + offA + f * 1024);                    \
    _Pragma("unroll") for (int n = 0; n < 2; ++n) {                          \
      bg##SET[n] = *(const bf16x8*)(rb + offG + n * 1024);                   \
      bu##SET[n] = *(const bf16x8*)(rb + offU + n * 1024); } }

#define G1_MFMA(SET)                                                         \
  { PRIO(1);                                                                 \
    _Pragma("unroll") for (int m = 0; m < 8; ++m)                            \
    _Pragma("unroll") for (int n = 0; n < 2; ++n) {                          \
      accg[m][n] = MFMA16(a##SET[m], bg##SET[n], accg[m][n]);                \
      accu[m][n] = MFMA16(a##SET[m], bu##SET[n], accu[m][n]); }              \
    PRIO(0); }

  bf16x8 aA[8], bgA[2], buA[2];
  bf16x8 aB[8], bgB[2], buB[2];

  G1_STAGE(0); G1_STAGE(1); G1_STAGE(2);
  vmw<8>(); BARRIER();
  G1_READS(A, 0);

  const int NT = H_DIM / 32;                  // 128
  for (int T = 0; T < NT - 4; T += 2) {
    vmw<4>(); BARRIER();                      // tile T+1 staged (all waves)
    G1_READS(B, T + 1);
    G1_STAGE(T + 3);
    G1_MFMA(A);                               // frags(T)
    vmw<4>(); BARRIER();                      // tile T+2 staged
    G1_READS(A, T + 2);
    G1_STAGE(T + 4);
    G1_MFMA(B);                               // frags(T+1)
  }
  vmw<4>(); BARRIER(); G1_READS(B, NT - 3); G1_STAGE(NT - 1); G1_MFMA(A);
  vmw<4>(); BARRIER(); G1_READS(A, NT - 2);                   G1_MFMA(B);
  vmw<0>(); BARRIER(); G1_READS(B, NT - 1);                   G1_MFMA(A);
  G1_MFMA(B);
#undef G1_STAGE
#undef G1_READS
#undef G1_MFMA

  const int r0 = tm * 256 + wm * 128 + kg * 4;
  const int c0 = tn * 128 + wn * 32 + lr;
#pragma unroll
  for (int m = 0; m < 8; ++m)
#pragma unroll
    for (int n = 0; n < 2; ++n)
#pragma unroll
      for (int e = 0; e < 4; ++e) {
        float g = accg[m][n][e];
        float u = accu[m][n][e];
        float s = g / (1.0f + __expf(-g));
        Aout[(size_t)(r0 + m * 16 + e) * I_DIM + c0 + n * 16] = (bf16_t)(s * u);
      }
}

// ===========================================================================
// GEMM2 (R9 down9 verbatim): D[M,H] = A Wd^T. BM=BN=256, BK=32,
// distance-1 register fragment prefetch, 4 bufs x 32 KiB, lead-3.
// ===========================================================================
__global__ __launch_bounds__(512, 2)
void k_down9(const bf16_t* __restrict__ Aa, const bf16_t* __restrict__ Wd,
             float* __restrict__ D)
{
  __shared__ __align__(1024) char lds[131072];
  const int tid = threadIdx.x, wave = tid >> 6, lane = tid & 63;
  const int lr = lane & 15, kg = lane >> 4;
  const int xm = ((lr >> 3) & 1) << 5;
  const int wm = wave >> 2, wn = wave & 3;
  const int wb = wave * 1024;

  const int bid = blockIdx.x;                 // grid = 256
  const int bq  = bid >> 3;                   // 0..31
  const int tn  = (bid & 7) * 2 + (bq >> 4);  // 0..15
  const int tm  = bq & 15;                    // 0..15

  const int srow  = tid >> 2;
  const int scolb = ((tid & 3) * 16) ^ (((tid >> 5) & 1) << 5);

  const bf16_t* gA = Aa + (size_t)(tm * 256 + srow) * I_DIM + (scolb >> 1);
  const bf16_t* gB = Wd + (size_t)(tn * 256 + srow) * I_DIM + (scolb >> 1);
  const size_t hI = (size_t)128 * I_DIM;

  const int ck   = (kg * 16) ^ xm;
  const int offA = (wm * 128 + lr) * 64 + ck;            // + f*1024
  const int offB = 16384 + (wn * 64 + lr) * 64 + ck;     // + n*1024, n=0..3

  const f32x4 vz = {0.f, 0.f, 0.f, 0.f};
  f32x4 acc[8][4];
#pragma unroll
  for (int m = 0; m < 8; ++m)
#pragma unroll
    for (int n = 0; n < 4; ++n) acc[m][n] = vz;

#define G2_STAGE(TT)                                                         \
  { char* sb = lds + (((TT) & 3) << 15) + wb;                                \
    const int kc = (TT) * 32;                                                \
    gl_lds16(gA + kc,      sb);                                              \
    gl_lds16(gA + hI + kc, sb + 8192);                                       \
    gl_lds16(gB + kc,      sb + 16384);                                      \
    gl_lds16(gB + hI + kc, sb + 24576); }

#define G2_READS(SET, TT)                                                    \
  { const char* rb = lds + (((TT) & 3) << 15);                               \
    _Pragma("unroll") for (int f = 0; f < 8; ++f)                            \
      a##SET[f] = *(const bf16x8*)(rb + offA + f * 1024);                    \
    _Pragma("unroll") for (int n = 0; n < 4; ++n)                            \
      b##SET[n] = *(const bf16x8*)(rb + offB + n * 1024); }

#define G2_MFMA(SET)                                                         \
  { PRIO(1);                                                                 \
    _Pragma("unroll") for (int m = 0; m < 8; ++m)                            \
    _Pragma("unroll") for (int n = 0; n < 4; ++n)                            \
      acc[m][n] = MFMA16(a##SET[m], b##SET[n], acc[m][n]);                   \
    PRIO(0); }

  bf16x8 aA[8], bA[4];
  bf16x8 aB[8], bB[4];

  G2_STAGE(0); G2_STAGE(1); G2_STAGE(2);
  vmw<8>(); BARRIER();
  G2_READS(A, 0);

  const int NT = I_DIM / 32;                  // 448
  for (int T = 0; T < NT - 4; T += 2) {
    vmw<4>(); BARRIER();
    G2_READS(B, T + 1);
    G2_STAGE(T + 3);
    G2_MFMA(A);
    vmw<4>(); BARRIER();
    G2_READS(A, T + 2);
    G2_STAGE(T + 4);
    G2_MFMA(B);
  }
  vmw<4>(); BARRIER(); G2_READS(B, NT - 3); G2_STAGE(NT - 1); G2_MFMA(A);
  vmw<4>(); BARRIER(); G2_READS(A, NT - 2);                   G2_MFMA(B);
  vmw<0>(); BARRIER(); G2_READS(B, NT - 1);                   G2_MFMA(A);
  G2_MFMA(B);
#undef G2_STAGE
#undef G2_READS
#undef G2_MFMA

  const int r0 = tm * 256 + wm * 128 + kg * 4;
  const int c0 = tn * 256 + wn * 64 + lr;
#pragma unroll
  for (int m = 0; m < 8; ++m)
#pragma unroll
    for (int n = 0; n < 4; ++n)
#pragma unroll
      for (int e = 0; e < 4; ++e)
        D[(size_t)(r0 + m * 16 + e) * H_DIM + c0 + n * 16] = acc[m][n][e];
}

// ---------------------------------------------------------------------------
extern "C" void kernel_launch(void* const* d_in, const int* in_sizes, int n_in,
                              void* d_out, int out_size, void* d_ws, size_t ws_size,
                              hipStream_t stream) {
  const float* x  = (const float*)d_in[0];
  const float* wg = (const float*)d_in[1];
  const float* wu = (const float*)d_in[2];
  const float* wd = (const float*)d_in[3];
  float* out = (float*)d_out;

  const size_t A_BYTES = (size_t)M_TOT * I_DIM * 2;
  const size_t X_BYTES = (size_t)M_TOT * H_DIM * 2;
  const size_t W_BYTES = (size_t)I_DIM * H_DIM * 2;
  char* ws = (char*)d_ws;
  bf16_t* Ab  = (bf16_t*)(ws);
  bf16_t* Xb  = (bf16_t*)(ws + A_BYTES);
  bf16_t* Wgb = (bf16_t*)(ws + A_BYTES + X_BYTES);
  bf16_t* Wub = (bf16_t*)(ws + A_BYTES + X_BYTES + W_BYTES);
  bf16_t* Wdb = Wgb;   // reuse after k_gateup9 consumed Wgb

  const long nX = (long)M_TOT * H_DIM / 4;
  const long nW = (long)I_DIM * H_DIM / 4;

  k_conv3<<<dim3(2048), dim3(256), 0, stream>>>(
      (const float4*)x, (const float4*)wg, (const float4*)wu,
      (bf16x4*)Xb, (bf16x4*)Wgb, (bf16x4*)Wub, nX, nW);

  k_gateup9<<<dim3(16 * 112), dim3(512), 0, stream>>>(Xb, Wgb, Wub, Ab);

  k_conv<<<dim3(2048), dim3(256), 0, stream>>>((const float4*)wd, (bf16x4*)Wdb, nW);

  k_down9<<<dim3(16 * 16), dim3(512), 0, stream>>>(Ab, Wdb, out);
}